// Round 1
// baseline (470.855 us; speedup 1.0000x reference)
//
#include <hip/hip_runtime.h>
#include <math.h>

#define TIME_N 65536
#define WIN    2048
#define HALFN  1024
#define NBINS  1025
#define NFRAMES 64

// ---------------------------------------------------------------------------
// Kernel 1: channel mixing  out[b,d,t] = sum_c x[b,c,t] * M[c,d]
// Tile: one batch b, 128 t-values, all 64 d per block. 256 threads.
// ---------------------------------------------------------------------------
#define TT 128
__global__ __launch_bounds__(256) void mix_kernel(const float* __restrict__ x,
                                                  const float* __restrict__ M,
                                                  float* __restrict__ out) {
    __shared__ float Ml[64 * 64];
    __shared__ float xt[64][136];   // row stride 136 floats = 544 B (16B aligned, breaks pow2)
    const int b   = blockIdx.y;
    const int t0  = blockIdx.x * TT;
    const int tid = threadIdx.x;

    for (int i = tid; i < 64 * 64; i += 256) Ml[i] = M[i];

    // load x tile: 64 rows x 128 floats = 2048 float4 / 256 threads = 8 each
    for (int r = 0; r < 8; ++r) {
        int fi = tid + r * 256;          // 0..2047
        int c  = fi >> 5;
        int t4 = fi & 31;
        float4 v = *reinterpret_cast<const float4*>(
            x + (size_t)(b * 64 + c) * TIME_N + t0 + t4 * 4);
        *reinterpret_cast<float4*>(&xt[c][t4 * 4]) = v;
    }
    __syncthreads();

    const int dq = tid >> 5;   // 0..7  -> d block of 8
    const int tq = tid & 31;   // 0..31 -> t lane

    float acc[8][4];
#pragma unroll
    for (int i = 0; i < 8; ++i)
#pragma unroll
        for (int j = 0; j < 4; ++j) acc[i][j] = 0.f;

    for (int c = 0; c < 64; ++c) {
        float xv[4];
#pragma unroll
        for (int j = 0; j < 4; ++j) xv[j] = xt[c][tq + 32 * j];
#pragma unroll
        for (int i = 0; i < 8; ++i) {
            float mv = Ml[c * 64 + dq * 8 + i];
#pragma unroll
            for (int j = 0; j < 4; ++j) acc[i][j] += xv[j] * mv;
        }
    }

#pragma unroll
    for (int i = 0; i < 8; ++i) {
        int d = dq * 8 + i;
        size_t baseo = (size_t)(b * 64 + d) * TIME_N + t0;
#pragma unroll
        for (int j = 0; j < 4; ++j) out[baseo + tq + 32 * j] = acc[i][j];
    }
}

// ---------------------------------------------------------------------------
// Kernel 2: per-(b,d) series: STFT -> per-bin frame recursion -> iSTFT ->
//           overlap-add -> gain -> tanh.   In-place on io (mixed signal).
// One workgroup (256 threads) per series; 256 series.
// ---------------------------------------------------------------------------
__device__ __forceinline__ float2 cmul(float2 a, float2 b) {
    return make_float2(a.x * b.x - a.y * b.y, a.x * b.y + a.y * b.x);
}

__global__ __launch_bounds__(256) void stft_chain_kernel(const float* __restrict__ transfer,
                                                         const float* __restrict__ gainp,
                                                         float* __restrict__ io) {
    __shared__ float  win[WIN];        //  8.0 KB Hann window
    __shared__ float2 tw [512];        //  4.0 KB e^{-2pi i j/1024}
    __shared__ float2 tw2[NBINS];      //  8.2 KB e^{-pi i k/1024}, k=0..1024
    __shared__ float  Tl [NBINS];      //  4.1 KB transfer row
    __shared__ float2 Cs [NBINS];      //  8.2 KB scan carry spectrum
    __shared__ float  tail[HALFN];     //  4.0 KB overlap-add carry
    __shared__ float2 zb [HALFN];      //  8.0 KB FFT working buffer

    const int bd  = blockIdx.x;        // 0..255  (b*64 + d)
    const int d   = bd & 63;
    const int tid = threadIdx.x;
    const float g = gainp[0];
    const size_t base = (size_t)bd * TIME_N;
    const float PI = 3.14159265358979323846f;

    for (int n = tid; n < WIN; n += 256)
        win[n] = 0.5f - 0.5f * cosf((2.0f * PI / WIN) * (float)n);
    for (int j = tid; j < 512; j += 256) {
        float s, c;
        sincosf(-(2.0f * PI / HALFN) * (float)j, &s, &c);
        tw[j] = make_float2(c, s);
    }
    for (int k = tid; k < NBINS; k += 256) {
        float s, c;
        sincosf((PI / HALFN) * (float)k, &s, &c);
        tw2[k] = make_float2(c, -s);
        Tl[k]  = transfer[d * NBINS + k];
        Cs[k]  = make_float2(0.f, 0.f);
    }
    for (int n = tid; n < HALFN; n += 256) tail[n] = 0.f;
    __syncthreads();

    for (int f = 0; f < NFRAMES; ++f) {
        // ---- pack real pairs, apply window, bit-reversed store ----
        for (int q = 0; q < 4; ++q) {
            int m = tid + q * 256;                 // 0..1023
            int t = f * HALFN + 2 * m;
            float2 v = make_float2(0.f, 0.f);
            if (t < TIME_N)                        // zero-pad tail of signal
                v = *reinterpret_cast<const float2*>(io + base + t);
            v.x *= win[2 * m];
            v.y *= win[2 * m + 1];
            zb[__brev((unsigned)m) >> 22] = v;
        }

        // ---- forward 1024-pt complex FFT (DIT, twiddles e^{-}) ----
        for (int s = 0; s < 10; ++s) {
            __syncthreads();
            int half = 1 << s;
#pragma unroll 2
            for (int q = 0; q < 2; ++q) {
                int i  = tid + q * 256;            // 0..511
                int j  = i & (half - 1);
                int i0 = ((i >> s) << (s + 1)) | j;
                int i1 = i0 + half;
                float2 a = zb[i0], bv = zb[i1];
                float2 w = tw[j << (9 - s)];
                float2 t2 = cmul(bv, w);
                zb[i0] = make_float2(a.x + t2.x, a.y + t2.y);
                zb[i1] = make_float2(a.x - t2.x, a.y - t2.y);
            }
        }
        __syncthreads();

        // ---- rfft post-process to X[k], then scan: O = (X + C)*T; C = O ----
        for (int k = tid; k < NBINS; k += 256) {
            float2 Zk = zb[k & (HALFN - 1)];
            float2 Zn = zb[(HALFN - k) & (HALFN - 1)];
            float2 Fe = make_float2(0.5f * (Zk.x + Zn.x), 0.5f * (Zk.y - Zn.y));
            float2 Fo = make_float2(0.5f * (Zk.y + Zn.y), -0.5f * (Zk.x - Zn.x));
            float2 X  = cmul(tw2[k], Fo);
            X.x += Fe.x; X.y += Fe.y;
            float2 O;
            O.x = (X.x + Cs[k].x) * Tl[k];
            O.y = (X.y + Cs[k].y) * Tl[k];
            Cs[k] = O;
        }
        __syncthreads();

        // ---- irfft pre-process: build Z'[m], bit-reversed store ----
        for (int m = tid; m < HALFN; m += 256) {
            float2 Om = Cs[m];
            float2 On = Cs[HALFN - m];             // index in [1,1024]
            float2 Fe  = make_float2(0.5f * (Om.x + On.x), 0.5f * (Om.y - On.y));
            float2 num = make_float2(0.5f * (Om.x - On.x), 0.5f * (Om.y + On.y));
            float2 w   = make_float2(tw2[m].x, -tw2[m].y);   // e^{+i pi m/1024}
            float2 Fo  = cmul(w, num);
            float2 Zp  = make_float2(Fe.x - Fo.y, Fe.y + Fo.x);
            zb[__brev((unsigned)m) >> 22] = Zp;
        }

        // ---- inverse 1024-pt complex FFT (DIT, twiddles e^{+}) ----
        for (int s = 0; s < 10; ++s) {
            __syncthreads();
            int half = 1 << s;
#pragma unroll 2
            for (int q = 0; q < 2; ++q) {
                int i  = tid + q * 256;
                int j  = i & (half - 1);
                int i0 = ((i >> s) << (s + 1)) | j;
                int i1 = i0 + half;
                float2 a = zb[i0], bv = zb[i1];
                float2 w = tw[j << (9 - s)];
                float2 t2 = make_float2(bv.x * w.x + bv.y * w.y,
                                        bv.y * w.x - bv.x * w.y);  // b * conj(w)
                zb[i0] = make_float2(a.x + t2.x, a.y + t2.y);
                zb[i1] = make_float2(a.x - t2.x, a.y - t2.y);
            }
        }
        __syncthreads();

        // ---- unpack (x2 real samples per complex), window, overlap-add,
        //      gain+tanh for first half; stash second half as new tail ----
        const float inv = 1.0f / (float)HALFN;
        for (int q = 0; q < 4; ++q) {
            int m = tid + q * 256;                 // 0..1023
            float2 zm = zb[m];
            float x0 = zm.x * inv * win[2 * m];
            float x1 = zm.y * inv * win[2 * m + 1];
            if (m < 512) {                         // output region [f*1024, f*1024+1024)
                int n0 = 2 * m;
                float v0 = tail[n0]     + x0;
                float v1 = tail[n0 + 1] + x1;
                float2 o = make_float2(tanhf(g * v0), tanhf(g * v1));
                *reinterpret_cast<float2*>(io + base + f * HALFN + n0) = o;
            } else {                               // new tail (same-thread indices as reads)
                int p = 2 * m - WIN + HALFN;       // 2m - 1024
                tail[p]     = x0;
                tail[p + 1] = x1;
            }
        }
        __syncthreads();
    }
}

// ---------------------------------------------------------------------------
extern "C" void kernel_launch(void* const* d_in, const int* in_sizes, int n_in,
                              void* d_out, int out_size, void* d_ws, size_t ws_size,
                              hipStream_t stream) {
    const float* x        = (const float*)d_in[0];   // (4,64,65536)
    const float* transfer = (const float*)d_in[1];   // (64,1025)
    const float* mixer    = (const float*)d_in[2];   // (64,64)
    const float* gain     = (const float*)d_in[3];   // (1,)
    float* out = (float*)d_out;                      // (4,64,65536)

    // 1) mix channels into d_out (used as the staging buffer)
    dim3 g1(TIME_N / TT, 4);
    mix_kernel<<<g1, 256, 0, stream>>>(x, mixer, out);

    // 2) fused STFT -> frame recursion -> iSTFT -> OLA -> tanh, in-place
    stft_chain_kernel<<<256, 256, 0, stream>>>(transfer, gain, out);
}

// Round 2
// 269.036 us; speedup vs baseline: 1.7502x; 1.7502x over previous
//
#include <hip/hip_runtime.h>
#include <math.h>

#define TIME_N 65536
#define WIN    2048
#define HALFN  1024
#define NBINS  1025
#define NFRAMES 64
#define FCHUNK 4
#define NCHUNK (NFRAMES / FCHUNK)   // 16

// ---------------------------------------------------------------------------
// Kernel 1: channel mixing  out[b,d,t] = sum_c x[b,c,t] * M[c,d]
// ---------------------------------------------------------------------------
#define TT 128
__global__ __launch_bounds__(256) void mix_kernel(const float* __restrict__ x,
                                                  const float* __restrict__ M,
                                                  float* __restrict__ out) {
    __shared__ float Ml[64 * 64];
    __shared__ float xt[64][136];
    const int b   = blockIdx.y;
    const int t0  = blockIdx.x * TT;
    const int tid = threadIdx.x;

    for (int i = tid; i < 64 * 64; i += 256) Ml[i] = M[i];

    for (int r = 0; r < 8; ++r) {
        int fi = tid + r * 256;
        int c  = fi >> 5;
        int t4 = fi & 31;
        float4 v = *reinterpret_cast<const float4*>(
            x + (size_t)(b * 64 + c) * TIME_N + t0 + t4 * 4);
        *reinterpret_cast<float4*>(&xt[c][t4 * 4]) = v;
    }
    __syncthreads();

    const int dq = tid >> 5;
    const int tq = tid & 31;

    float acc[8][4];
#pragma unroll
    for (int i = 0; i < 8; ++i)
#pragma unroll
        for (int j = 0; j < 4; ++j) acc[i][j] = 0.f;

    for (int c = 0; c < 64; ++c) {
        float xv[4];
#pragma unroll
        for (int j = 0; j < 4; ++j) xv[j] = xt[c][tq + 32 * j];
#pragma unroll
        for (int i = 0; i < 8; ++i) {
            float mv = Ml[c * 64 + dq * 8 + i];
#pragma unroll
            for (int j = 0; j < 4; ++j) acc[i][j] += xv[j] * mv;
        }
    }

#pragma unroll
    for (int i = 0; i < 8; ++i) {
        int d = dq * 8 + i;
        size_t baseo = (size_t)(b * 64 + d) * TIME_N + t0;
#pragma unroll
        for (int j = 0; j < 4; ++j) out[baseo + tq + 32 * j] = acc[i][j];
    }
}

// ---------------------------------------------------------------------------
// Kernel 2: fused STFT -> per-bin frame recursion -> iSTFT -> OLA -> tanh.
// 256 blocks (one per (b,d) series) x 1024 threads. 4 frames per chunk:
// 4 concurrent 1024-pt radix-4 Stockham FFTs (one per 256-thread group).
// Per-bin scan carry + transfer + OLA tail live in registers.
// ---------------------------------------------------------------------------
__device__ __forceinline__ int P(int i) { return i + (i >> 4); }   // pad-16
#define BUFSZ 1088   // P(1023) = 1086

__device__ __forceinline__ float2 cadd(float2 a, float2 b){return make_float2(a.x+b.x, a.y+b.y);}
__device__ __forceinline__ float2 csub(float2 a, float2 b){return make_float2(a.x-b.x, a.y-b.y);}
__device__ __forceinline__ float2 cmul(float2 a, float2 b){return make_float2(a.x*b.x - a.y*b.y, a.x*b.y + a.y*b.x);}

// 1024-pt in-place radix-4 Stockham; SGN=-1 fwd (e^-), +1 inv (e^+).
// lt in [0,256). 2 barriers per stage (read-all / write-all discipline).
template<int SGN>
__device__ __forceinline__ void fft1024(float2* b, int lt) {
    const float PI2 = 6.2831853071795864769f;
#pragma unroll
    for (int k = 0; k < 5; ++k) {
        const int s = 1 << (2 * k);
        const int n = 1024 >> (2 * k);
        const int p = lt >> (2 * k);
        const int q = lt & (s - 1);
        float2 a  = b[P(lt)];
        float2 bv = b[P(lt + 256)];
        float2 cv = b[P(lt + 512)];
        float2 dv = b[P(lt + 768)];
        float ang = (float)SGN * PI2 * (float)p / (float)n;
        float sn, cs; __sincosf(ang, &sn, &cs);
        float2 w1 = make_float2(cs, sn);
        float2 w2 = cmul(w1, w1);
        float2 w3 = cmul(w1, w2);
        float2 apc = cadd(a, cv), amc = csub(a, cv);
        float2 bpd = cadd(bv, dv), bmd = csub(bv, dv);
        float2 sj = make_float2(-(float)SGN * bmd.y, (float)SGN * bmd.x); // SGN*j*(b-d)
        float2 y0 = cadd(apc, bpd);
        float2 y1 = cmul(w1, cadd(amc, sj));
        float2 y2 = cmul(w2, csub(apc, bpd));
        float2 y3 = cmul(w3, csub(amc, sj));
        __syncthreads();
        int wb = q + 4 * s * p;
        b[P(wb)]         = y0;
        b[P(wb + s)]     = y1;
        b[P(wb + 2 * s)] = y2;
        b[P(wb + 3 * s)] = y3;
        __syncthreads();
    }
}

__global__ __launch_bounds__(1024) void stft_chain_kernel(
    const float* __restrict__ transfer,
    const float* __restrict__ gainp,
    float* __restrict__ io)
{
    __shared__ float2 buf[FCHUNK][BUFSZ];   // ~34.8 KB
    __shared__ float2 onys[FCHUNK];         // Nyquist-bin O per frame

    const int bd  = blockIdx.x;        // 0..255
    const int d   = bd & 63;
    const int tid = threadIdx.x;       // 0..1023
    const int lf  = tid >> 8;          // which frame's FFT this thread works
    const int lt  = tid & 255;         // butterfly index within that FFT
    const float g = gainp[0];
    const size_t base = (size_t)bd * TIME_N;
    const float PI  = 3.14159265358979323846f;
    const float inv = 1.0f / 1024.0f;

    // --- persistent per-thread state ---
    const float Treg = transfer[(size_t)d * NBINS + tid];                 // bin tid
    const float Tny  = (tid == 0) ? transfer[(size_t)d * NBINS + HALFN] : 0.f;
    float2 C   = make_float2(0.f, 0.f);      // scan carry, bin tid
    float2 Cny = make_float2(0.f, 0.f);      // scan carry, bin 1024 (thread 0)
    float tailr = 0.f;                       // OLA carry for sample position tid

    // --- window / twiddle constants (win[n] = 0.5 - 0.5 cos(pi n / 1024)) ---
    const float wA  = 0.5f - 0.5f * __cosf((PI / HALFN) * (float)(2 * tid));
    const float wB  = 0.5f - 0.5f * __cosf((PI / HALFN) * (float)(2 * tid + 1));
    const float wU0 = 0.5f - 0.5f * __cosf((PI / HALFN) * (float)tid);
    const float wU1 = 0.5f - 0.5f * __cosf((PI / HALFN) * (float)(HALFN + tid));
    float s2v, c2v; __sincosf((PI / HALFN) * (float)tid, &s2v, &c2v);
    const float e2c = c2v, e2s = -s2v;       // e^{-i pi k/1024} = (e2c, e2s)

    for (int ch = 0; ch < NCHUNK; ++ch) {
        // ---------- load + window ----------
#pragma unroll
        for (int f = 0; f < FCHUNK; ++f) {
            int fr = ch * FCHUNK + f;
            int t  = fr * HALFN + 2 * tid;
            float2 v = make_float2(0.f, 0.f);
            if (t < TIME_N)
                v = *reinterpret_cast<const float2*>(io + base + t);
            v.x *= wA; v.y *= wB;
            buf[f][P(tid)] = v;
        }
        __syncthreads();

        // ---------- 4 concurrent forward FFTs ----------
        fft1024<-1>(&buf[lf][0], lt);

        // ---------- rfft post-process + per-bin scan (registers) ----------
        float2 Zk[FCHUNK], Zn[FCHUNK];
#pragma unroll
        for (int f = 0; f < FCHUNK; ++f) {
            Zk[f] = buf[f][P(tid)];
            Zn[f] = buf[f][P((HALFN - tid) & (HALFN - 1))];
        }
        __syncthreads();
#pragma unroll
        for (int f = 0; f < FCHUNK; ++f) {
            float2 Fe = make_float2(0.5f * (Zk[f].x + Zn[f].x), 0.5f * (Zk[f].y - Zn[f].y));
            float2 Fo = make_float2(0.5f * (Zk[f].y + Zn[f].y), -0.5f * (Zk[f].x - Zn[f].x));
            float2 X  = cmul(make_float2(e2c, e2s), Fo);
            X.x += Fe.x; X.y += Fe.y;
            float2 O;
            O.x = (X.x + C.x) * Treg;
            O.y = (X.y + C.y) * Treg;
            C = O;
            buf[f][P(tid)] = O;
        }
        if (tid == 0) {
#pragma unroll
            for (int f = 0; f < FCHUNK; ++f) {
                float Xny = Zk[f].x - Zk[f].y;         // Zk[f] == z_f[0]
                Cny.x = (Xny + Cny.x) * Tny;
                Cny.y = Cny.y * Tny;
                onys[f] = Cny;
            }
        }
        __syncthreads();

        // ---------- irfft pre-process ----------
        float2 Om[FCHUNK], On[FCHUNK];
#pragma unroll
        for (int f = 0; f < FCHUNK; ++f) {
            Om[f] = buf[f][P(tid)];
            On[f] = (tid == 0) ? onys[f] : buf[f][P(HALFN - tid)];
        }
        __syncthreads();
#pragma unroll
        for (int f = 0; f < FCHUNK; ++f) {
            float2 Fe  = make_float2(0.5f * (Om[f].x + On[f].x), 0.5f * (Om[f].y - On[f].y));
            float2 num = make_float2(0.5f * (Om[f].x - On[f].x), 0.5f * (Om[f].y + On[f].y));
            float2 Fo  = cmul(make_float2(e2c, -e2s), num);  // e^{+i pi m/1024}
            buf[f][P(tid)] = make_float2(Fe.x - Fo.y, Fe.y + Fo.x);
        }
        __syncthreads();

        // ---------- 4 concurrent inverse FFTs ----------
        fft1024<1>(&buf[lf][0], lt);

        // ---------- unpack + OLA + gain + tanh (tail in register) ----------
#pragma unroll
        for (int f = 0; f < FCHUNK; ++f) {
            int fr = ch * FCHUNK + f;
            float2 zlo = buf[f][P(tid >> 1)];
            float2 zhi = buf[f][P(512 + (tid >> 1))];
            float xs = (tid & 1) ? zlo.y : zlo.x;
            float xh = (tid & 1) ? zhi.y : zhi.x;
            float v  = tailr + xs * inv * wU0;
            io[base + (size_t)fr * HALFN + tid] = tanhf(g * v);
            tailr = xh * inv * wU1;
        }
        __syncthreads();
    }
}

// ---------------------------------------------------------------------------
extern "C" void kernel_launch(void* const* d_in, const int* in_sizes, int n_in,
                              void* d_out, int out_size, void* d_ws, size_t ws_size,
                              hipStream_t stream) {
    const float* x        = (const float*)d_in[0];   // (4,64,65536)
    const float* transfer = (const float*)d_in[1];   // (64,1025)
    const float* mixer    = (const float*)d_in[2];   // (64,64)
    const float* gain     = (const float*)d_in[3];   // (1,)
    float* out = (float*)d_out;                      // (4,64,65536)

    dim3 g1(TIME_N / TT, 4);
    mix_kernel<<<g1, 256, 0, stream>>>(x, mixer, out);

    stft_chain_kernel<<<256, 1024, 0, stream>>>(transfer, gain, out);
}